// Round 3
// baseline (132.365 us; speedup 1.0000x reference)
//
#include <hip/hip_runtime.h>
#include <hip/hip_fp16.h>
#include <stdint.h>

#define NROWS 4096
#define DIM   512
#define TILE  128
#define NBLK  32            // NROWS / TILE
#define NPAIR 528           // NBLK*(NBLK+1)/2
#define KSTEPS 16           // DIM / 32

typedef float    f32x4 __attribute__((ext_vector_type(4)));
typedef _Float16 f16x8 __attribute__((ext_vector_type(8)));

// workspace layout (bytes)
#define OFF_XH   0u
#define OFF_SQ   (NROWS * DIM * 2u)          // 4,194,304
#define OFF_LAB  (OFF_SQ + NROWS * 4u)
#define OFF_ACC  (OFF_LAB + NROWS * 4u)

// ---------------- prep: fp32 -> fp16, sq rows (fp32 exact), labels -> i32, zero accum
__global__ __launch_bounds__(256) void prep_kernel(
    const float* __restrict__ X, const long long* __restrict__ lab,
    unsigned short* __restrict__ Xh, float* __restrict__ sq,
    int* __restrict__ labi, float* __restrict__ accum)
{
  int t = threadIdx.x;
  int gid = blockIdx.x * 256 + t;
  if (gid < 4) accum[gid] = 0.0f;               // sum1, sum2, cnt(bits), done-counter
  if (gid < NROWS) labi[gid] = (int)lab[gid];

  int wave = t >> 6, lane = t & 63;
  int row = blockIdx.x * 4 + wave;              // 1024 blocks * 4 rows
  const float4* Xr = (const float4*)(X + (size_t)row * DIM);
  float4 a = Xr[lane * 2];
  float4 b = Xr[lane * 2 + 1];

  uint4 pk;
  pk.x = (unsigned)__half_as_ushort(__float2half(a.x)) | ((unsigned)__half_as_ushort(__float2half(a.y)) << 16);
  pk.y = (unsigned)__half_as_ushort(__float2half(a.z)) | ((unsigned)__half_as_ushort(__float2half(a.w)) << 16);
  pk.z = (unsigned)__half_as_ushort(__float2half(b.x)) | ((unsigned)__half_as_ushort(__float2half(b.y)) << 16);
  pk.w = (unsigned)__half_as_ushort(__float2half(b.z)) | ((unsigned)__half_as_ushort(__float2half(b.w)) << 16);
  *(uint4*)(Xh + (size_t)row * DIM + lane * 8) = pk;

  float s = a.x*a.x + a.y*a.y + a.z*a.z + a.w*a.w
          + b.x*b.x + b.y*b.y + b.z*b.z + b.w*b.w;
  #pragma unroll
  for (int off = 32; off; off >>= 1) s += __shfl_down(s, off, 64);
  if (lane == 0) sq[row] = s;
}

// ---------------- main: register-direct X*X^T (no LDS staging, no K-loop barriers)
// A/B fragment layout for mfma_f32_16x16x32: lane holds row (lane&15), k = (lane>>4)*8 + j
// -> 16B contiguous per lane, loadable straight from row-major global.
__global__ __launch_bounds__(256, 2) void pair_kernel(
    const unsigned short* __restrict__ Xh, const float* __restrict__ sq,
    const int* __restrict__ labi, const float* __restrict__ marginp,
    float* __restrict__ accum, float* __restrict__ out)
{
  __shared__ float sRow[TILE], sCol[TILE];
  __shared__ int   lRow[TILE], lCol[TILE];
  __shared__ float rs1[4], rs2[4];
  __shared__ int   rc[4];

  int t = threadIdx.x;

  // linear block -> (bi, bj) with bi <= bj
  int rem = blockIdx.x, bi = 0;
  while (rem >= (NBLK - bi)) { rem -= (NBLK - bi); bi++; }
  int bj = bi + rem;

  // epilogue metadata -> LDS (single barrier after the K-loop)
  if (t < TILE) {
    sRow[t] = sq[bi * TILE + t];
    lRow[t] = labi[bi * TILE + t];
  } else {
    int u = t - TILE;
    sCol[u] = sq[bj * TILE + u];
    lCol[u] = labi[bj * TILE + u];
  }

  int wave = t >> 6, lane = t & 63;
  int quad = lane >> 4, ml = lane & 15;
  int waveRow = (wave >> 1) * 64, waveCol = (wave & 1) * 64;

  // per-lane fragment base pointers (8 streams, k advances by 64B each step)
  const f16x8* ap[4];
  const f16x8* bp[4];
  #pragma unroll
  for (int r = 0; r < 4; ++r) {
    int grow = bi * TILE + waveRow + r * 16 + ml;
    int gcol = bj * TILE + waveCol + r * 16 + ml;
    ap[r] = (const f16x8*)(Xh + (size_t)grow * DIM + quad * 8);
    bp[r] = (const f16x8*)(Xh + (size_t)gcol * DIM + quad * 8);
  }

  f32x4 acc[4][4] = {};

  #pragma unroll
  for (int ks = 0; ks < KSTEPS; ++ks) {
    f16x8 af[4], bf[4];
    #pragma unroll
    for (int r = 0; r < 4; ++r) af[r] = ap[r][ks * 4];   // 32 halves = 4 f16x8 per step
    #pragma unroll
    for (int c = 0; c < 4; ++c) bf[c] = bp[c][ks * 4];
    #pragma unroll
    for (int r = 0; r < 4; ++r)
      #pragma unroll
      for (int c = 0; c < 4; ++c)
        acc[r][c] = __builtin_amdgcn_mfma_f32_16x16x32_f16(af[r], bf[c], acc[r][c], 0, 0, 0);
  }

  __syncthreads();   // sRow/sCol/lRow/lCol visible

  // ---- fused loss epilogue
  float margin = *marginp;
  float s1 = 0.f, s2 = 0.f;
  int cnt = 0;
  #pragma unroll
  for (int c = 0; c < 4; ++c) {
    int col = waveCol + c * 16 + ml;
    float sqc = sCol[col];
    int lc = lCol[col];
    #pragma unroll
    for (int r = 0; r < 4; ++r) {
      int rbase = waveRow + r * 16 + quad * 4;   // C/D: row=(lane>>4)*4+reg, col=lane&15
      #pragma unroll
      for (int i = 0; i < 4; ++i) {
        int row = rbase + i;
        float d = sRow[row] + sqc - 2.0f * acc[r][c][i];
        d = fmaxf(d, 0.0f);
        if (lRow[row] == lc) { s1 += d; cnt++; }
        else                 { s2 += fmaxf(margin - d, 0.0f); }
      }
    }
  }

  #pragma unroll
  for (int off = 32; off; off >>= 1) {
    s1  += __shfl_down(s1, off, 64);
    s2  += __shfl_down(s2, off, 64);
    cnt += __shfl_down(cnt, off, 64);
  }
  if (lane == 0) { rs1[wave] = s1; rs2[wave] = s2; rc[wave] = cnt; }
  __syncthreads();
  if (t == 0) {
    float f = (bi == bj) ? 1.f : 2.f;
    float S1 = 0.f, S2 = 0.f;
    int C = 0;
    for (int w = 0; w < 4; ++w) { S1 += rs1[w]; S2 += rs2[w]; C += rc[w]; }
    atomicAdd(&accum[0], S1 * f);
    atomicAdd(&accum[1], S2 * f);
    atomicAdd((unsigned*)accum + 2, (unsigned)C * (unsigned)((bi == bj) ? 1 : 2));
    __threadfence();
    unsigned prev = atomicAdd((unsigned*)accum + 3, 1u);
    if (prev == NPAIR - 1) {
      float s1v = atomicAdd(&accum[0], 0.0f);
      float s2v = atomicAdd(&accum[1], 0.0f);
      unsigned c1 = atomicAdd((unsigned*)accum + 2, 0u);
      double zn1 = (double)c1;
      double zn2 = (double)NROWS * (double)NROWS - zn1;
      out[0] = (float)(0.5 * ((double)s1v / zn1 + (double)s2v / zn2));
    }
  }
}

extern "C" void kernel_launch(void* const* d_in, const int* in_sizes, int n_in,
                              void* d_out, int out_size, void* d_ws, size_t ws_size,
                              hipStream_t stream) {
  const float*     X      = (const float*)d_in[0];
  const long long* lab    = (const long long*)d_in[1];
  const float*     margin = (const float*)d_in[2];
  float*           out    = (float*)d_out;

  char* ws = (char*)d_ws;
  unsigned short* Xh   = (unsigned short*)(ws + OFF_XH);
  float*          sq   = (float*)(ws + OFF_SQ);
  int*            labi = (int*)(ws + OFF_LAB);
  float*          accum= (float*)(ws + OFF_ACC);

  prep_kernel<<<NROWS / 4, 256, 0, stream>>>(X, lab, Xh, sq, labi, accum);
  pair_kernel<<<NPAIR, 256, 0, stream>>>(Xh, sq, labi, margin, accum, out);
}